// Round 1
// baseline (383.926 us; speedup 1.0000x reference)
//
#include <hip/hip_runtime.h>
#include <hip/hip_bf16.h>

typedef __bf16 bf16;
typedef __bf16 bf16x8 __attribute__((ext_vector_type(8)));
typedef __bf16 bf16x4 __attribute__((ext_vector_type(4)));
typedef float  f32x4  __attribute__((ext_vector_type(4)));

constexpr int BB = 2, C = 512, NN = 8192, CK = 128;

// ---------------- Kernel 1: QKV projection ----------------
// q[b][n][o] = sum_c W[o][c] * x[b][c][n] + bias[o], stored bf16 [B][N][128]
__global__ __launch_bounds__(256) void k_qkv(
    const float* __restrict__ x,
    const float* __restrict__ Wq, const float* __restrict__ bq,
    const float* __restrict__ Wk, const float* __restrict__ bk,
    const float* __restrict__ Wv, const float* __restrict__ bv,
    bf16* __restrict__ qkv_ws)
{
    const int t = threadIdx.x;
    const int lane = t & 63, w = t >> 6;
    const int lr = lane & 15, lg = lane >> 4;
    const int n0 = blockIdx.x * 128;
    const int which = blockIdx.y;
    const int b = blockIdx.z;
    const float* W    = which == 0 ? Wq : (which == 1 ? Wk : Wv);
    const float* bias = which == 0 ? bq : (which == 1 ? bk : bv);
    bf16* out = qkv_ws + (size_t)which * BB * NN * CK;

    // [tok][c] and [o][c] tiles, 32 bf16 per row (64B), swizzle ((row&3)<<4)
    __shared__ __align__(16) char s_xT[128 * 64];
    __shared__ __align__(16) char s_w [128 * 64];

    f32x4 acc[2][8];
#pragma unroll
    for (int m = 0; m < 2; m++)
#pragma unroll
        for (int j = 0; j < 8; j++) acc[m][j] = (f32x4){0.f, 0.f, 0.f, 0.f};

    const float* xb = x + (size_t)b * C * NN;

    for (int kt = 0; kt < C; kt += 32) {
        __syncthreads();
        // stage x^T tile: tokens n0..n0+127, channels kt..kt+31
        {
            int col4 = (t & 31) * 4;   // token base (4 tokens)
            int rbase = t >> 5;        // channel-in-tile base
#pragma unroll
            for (int p = 0; p < 4; p++) {
                int c = rbase + p * 8;
                float4 v = *(const float4*)(xb + (size_t)(kt + c) * NN + n0 + col4);
                float vv[4] = {v.x, v.y, v.z, v.w};
#pragma unroll
                for (int j = 0; j < 4; j++) {
                    int tok = col4 + j;
                    int off = (tok * 64 + c * 2) ^ ((tok & 3) << 4);
                    *(bf16*)(s_xT + off) = (bf16)vv[j];
                }
            }
        }
        // stage W tile: o 0..127, channels kt..kt+31
        {
            int c4 = (t & 7) * 4;
            int obase = t >> 3;
#pragma unroll
            for (int p = 0; p < 4; p++) {
                int o = obase + p * 32;
                float4 v = *(const float4*)(W + (size_t)o * C + kt + c4);
                bf16x4 b4 = { (bf16)v.x, (bf16)v.y, (bf16)v.z, (bf16)v.w };
                int off = (o * 64 + c4 * 2) ^ ((o & 3) << 4);
                *(bf16x4*)(s_w + off) = b4;
            }
        }
        __syncthreads();
        bf16x8 af[2], bfr[8];
#pragma unroll
        for (int m = 0; m < 2; m++) {
            int row = w * 32 + m * 16 + lr;
            int off = (row * 64 + lg * 16) ^ ((row & 3) << 4);
            af[m] = *(const bf16x8*)(s_xT + off);
        }
#pragma unroll
        for (int j = 0; j < 8; j++) {
            int row = j * 16 + lr;
            int off = (row * 64 + lg * 16) ^ ((row & 3) << 4);
            bfr[j] = *(const bf16x8*)(s_w + off);
        }
#pragma unroll
        for (int m = 0; m < 2; m++)
#pragma unroll
            for (int j = 0; j < 8; j++)
                acc[m][j] = __builtin_amdgcn_mfma_f32_16x16x32_bf16(af[m], bfr[j], acc[m][j], 0, 0, 0);
    }
    // epilogue: + bias, store bf16 [b][n][o]
#pragma unroll
    for (int m = 0; m < 2; m++)
#pragma unroll
        for (int j = 0; j < 8; j++) {
            int o = j * 16 + lr;
            float bia = bias[o];
#pragma unroll
            for (int r = 0; r < 4; r++) {
                int tok = n0 + w * 32 + m * 16 + lg * 4 + r;
                out[((size_t)b * NN + tok) * CK + o] = (bf16)(acc[m][j][r] + bia);
            }
        }
}

// ---------------- Kernel 2: flash attention ----------------
// Q-tile 64 rows/block (4 waves x 16 rows), KV tiles of 64, online softmax.
__global__ __launch_bounds__(256) void k_attn(const bf16* __restrict__ qkv_ws,
                                              bf16* __restrict__ ao)
{
    const int t = threadIdx.x;
    const int lane = t & 63, w = t >> 6;
    const int lr = lane & 15, lg = lane >> 4;
    const int b = blockIdx.y;
    const int q0 = blockIdx.x * 64;

    const bf16* qg = qkv_ws;
    const bf16* kg = qkv_ws + (size_t)BB * NN * CK;
    const bf16* vg = qkv_ws + (size_t)2 * BB * NN * CK;

    __shared__ __align__(16) char s_k[64 * 256];     // [key][dim], swz ((row&7)<<4)
    __shared__ __align__(16) char s_vt[128 * 128];   // [dim][key], swz (((d&7)^((d>>3)&7))<<4)
    __shared__ __align__(16) char s_p[4][16 * 128];  // per-wave [row][key], swz (((row>>2)&3)<<5)

    // Q fragments in registers (16 rows x 128 dims per wave)
    bf16x8 qf[4];
    {
        int qrow = q0 + w * 16 + lr;
        const bf16* qp = qg + ((size_t)b * NN + qrow) * CK;
#pragma unroll
        for (int ks = 0; ks < 4; ks++)
            qf[ks] = *(const bf16x8*)(qp + ks * 32 + lg * 8);
    }

    f32x4 oacc[8];
#pragma unroll
    for (int j = 0; j < 8; j++) oacc[j] = (f32x4){0.f, 0.f, 0.f, 0.f};
    float mrun[4], lrun[4];
#pragma unroll
    for (int r = 0; r < 4; r++) { mrun[r] = -1e30f; lrun[r] = 0.f; }

    const float scale = 0.08838834764831845f;  // 128^-0.5

    for (int k0 = 0; k0 < NN; k0 += 64) {
        __syncthreads();
        // stage K tile [64][128]
        {
            int chunk = t & 15, row = t >> 4;
#pragma unroll
            for (int p = 0; p < 4; p++) {
                int kr = row + p * 16;
                bf16x8 v = *(const bf16x8*)(kg + ((size_t)b * NN + k0 + kr) * CK + chunk * 8);
                int off = (kr * 256 + chunk * 16) ^ ((kr & 7) << 4);
                *(bf16x8*)(s_k + off) = v;
            }
        }
        // stage V^T tile [128][64]
        {
            int chunk = t & 15, row = t >> 4;
#pragma unroll
            for (int p = 0; p < 4; p++) {
                int kr = row + p * 16;
                bf16x8 v = *(const bf16x8*)(vg + ((size_t)b * NN + k0 + kr) * CK + chunk * 8);
#pragma unroll
                for (int j = 0; j < 8; j++) {
                    int d = chunk * 8 + j;
                    int off = (d * 128 + kr * 2) ^ ((((d & 7) ^ ((d >> 3) & 7))) << 4);
                    *(bf16*)(s_vt + off) = v[j];
                }
            }
        }
        __syncthreads();
        // S = (Q K^T) * scale   [16 rows][64 keys] per wave
        f32x4 sa[4];
#pragma unroll
        for (int j = 0; j < 4; j++) sa[j] = (f32x4){0.f, 0.f, 0.f, 0.f};
#pragma unroll
        for (int ks = 0; ks < 4; ks++) {
#pragma unroll
            for (int j = 0; j < 4; j++) {
                int kr = j * 16 + lr;
                int off = (kr * 256 + (ks * 32 + lg * 8) * 2) ^ ((kr & 7) << 4);
                bf16x8 kf = *(const bf16x8*)(s_k + off);
                sa[j] = __builtin_amdgcn_mfma_f32_16x16x32_bf16(qf[ks], kf, sa[j], 0, 0, 0);
            }
        }
#pragma unroll
        for (int j = 0; j < 4; j++) sa[j] *= scale;
        // online softmax; lane's rows are lg*4 + r
#pragma unroll
        for (int r = 0; r < 4; r++) {
            float mx = fmaxf(fmaxf(sa[0][r], sa[1][r]), fmaxf(sa[2][r], sa[3][r]));
#pragma unroll
            for (int m = 8; m > 0; m >>= 1) mx = fmaxf(mx, __shfl_xor(mx, m));
            float mnew = fmaxf(mrun[r], mx);
            float corr = __expf(mrun[r] - mnew);
            mrun[r] = mnew;
            float psum = 0.f;
            bf16 pb[4];
#pragma unroll
            for (int j = 0; j < 4; j++) {
                float p = __expf(sa[j][r] - mnew);
                psum += p;
                pb[j] = (bf16)p;
            }
#pragma unroll
            for (int m = 8; m > 0; m >>= 1) psum += __shfl_xor(psum, m);
            lrun[r] = lrun[r] * corr + psum;
#pragma unroll
            for (int j = 0; j < 8; j++) oacc[j][r] *= corr;
            int prow = lg * 4 + r;
#pragma unroll
            for (int j = 0; j < 4; j++) {
                int off = (prow * 128 + (j * 16 + lr) * 2) ^ (((prow >> 2) & 3) << 5);
                *(bf16*)(s_p[w] + off) = pb[j];
            }
        }
        // O += P V
#pragma unroll
        for (int ks = 0; ks < 2; ks++) {
            int poff = (lr * 128 + (ks * 32 + lg * 8) * 2) ^ (((lr >> 2) & 3) << 5);
            bf16x8 pf = *(const bf16x8*)(s_p[w] + poff);
#pragma unroll
            for (int j = 0; j < 8; j++) {
                int d = j * 16 + lr;
                int voff = (d * 128 + (ks * 32 + lg * 8) * 2) ^ ((((d & 7) ^ ((d >> 3) & 7))) << 4);
                bf16x8 vf = *(const bf16x8*)(s_vt + voff);
                oacc[j] = __builtin_amdgcn_mfma_f32_16x16x32_bf16(pf, vf, oacc[j], 0, 0, 0);
            }
        }
    }
    // epilogue: normalize, store bf16 [b][n][d]
#pragma unroll
    for (int j = 0; j < 8; j++)
#pragma unroll
        for (int r = 0; r < 4; r++) {
            int qrow = q0 + w * 16 + lg * 4 + r;
            int d = j * 16 + lr;
            ao[((size_t)b * NN + qrow) * CK + d] = (bf16)(oacc[j][r] / lrun[r]);
        }
}

// ---------------- Kernel 3: folded output projection + bias + residual ----------------
// y[b][o][n] = sum_c Woe[o][c]*ao[b][n][c] + bo[o] + x[b][o][n], Woe = sum of 4 col-blocks of Wo
__global__ __launch_bounds__(256) void k_out(
    const float* __restrict__ x, const float* __restrict__ Wo, const float* __restrict__ bo,
    const bf16* __restrict__ ao, float* __restrict__ y)
{
    const int t = threadIdx.x;
    const int lane = t & 63, w = t >> 6;
    const int lr = lane & 15, lg = lane >> 4;
    const int n0 = blockIdx.x * 128;
    const int o0 = blockIdx.y * 64;
    const int b = blockIdx.z;

    __shared__ __align__(16) char s_w[64 * 256];   // Woe [o][c], swz ((row&7)<<4)
    __shared__ __align__(16) char s_a[128 * 256];  // ao  [n][c], swz ((row&7)<<4)

    // stage folded Wo
    {
        int c4 = (t & 31) * 4, rbase = t >> 5;
#pragma unroll
        for (int p = 0; p < 8; p++) {
            int row = rbase + p * 8;
            const float* wp = Wo + (size_t)(o0 + row) * C + c4;
            float4 a0 = *(const float4*)(wp);
            float4 a1 = *(const float4*)(wp + 128);
            float4 a2 = *(const float4*)(wp + 256);
            float4 a3 = *(const float4*)(wp + 384);
            bf16x4 r4 = { (bf16)(a0.x + a1.x + a2.x + a3.x), (bf16)(a0.y + a1.y + a2.y + a3.y),
                          (bf16)(a0.z + a1.z + a2.z + a3.z), (bf16)(a0.w + a1.w + a2.w + a3.w) };
            int off = (row * 256 + c4 * 2) ^ ((row & 7) << 4);
            *(bf16x4*)(s_w + off) = r4;
        }
    }
    // stage ao tile [128 n][128 c]
    {
        int chunk = t & 15, rbase = t >> 4;
#pragma unroll
        for (int p = 0; p < 8; p++) {
            int row = rbase + p * 16;
            bf16x8 v = *(const bf16x8*)(ao + ((size_t)b * NN + n0 + row) * CK + chunk * 8);
            int off = (row * 256 + chunk * 16) ^ ((row & 7) << 4);
            *(bf16x8*)(s_a + off) = v;
        }
    }
    __syncthreads();

    f32x4 acc[8];
#pragma unroll
    for (int j = 0; j < 8; j++) acc[j] = (f32x4){0.f, 0.f, 0.f, 0.f};
#pragma unroll
    for (int ks = 0; ks < 4; ks++) {
        int row = w * 16 + lr;
        int aoff = (row * 256 + (ks * 32 + lg * 8) * 2) ^ ((row & 7) << 4);
        bf16x8 wf = *(const bf16x8*)(s_w + aoff);
#pragma unroll
        for (int j = 0; j < 8; j++) {
            int nrow = j * 16 + lr;
            int boff = (nrow * 256 + (ks * 32 + lg * 8) * 2) ^ ((nrow & 7) << 4);
            bf16x8 af = *(const bf16x8*)(s_a + boff);
            acc[j] = __builtin_amdgcn_mfma_f32_16x16x32_bf16(wf, af, acc[j], 0, 0, 0);
        }
    }
    // epilogue: + bo + x (residual), fp32 out
#pragma unroll
    for (int j = 0; j < 8; j++) {
        int n = n0 + j * 16 + lr;
#pragma unroll
        for (int r = 0; r < 4; r++) {
            int o = o0 + w * 16 + lg * 4 + r;
            size_t idx = ((size_t)b * C + o) * NN + n;
            y[idx] = acc[j][r] + bo[o] + x[idx];
        }
    }
}

extern "C" void kernel_launch(void* const* d_in, const int* in_sizes, int n_in,
                              void* d_out, int out_size, void* d_ws, size_t ws_size,
                              hipStream_t stream)
{
    const float* x  = (const float*)d_in[0];
    const float* Wq = (const float*)d_in[1];
    const float* bq = (const float*)d_in[2];
    const float* Wk = (const float*)d_in[3];
    const float* bk = (const float*)d_in[4];
    const float* Wv = (const float*)d_in[5];
    const float* bv = (const float*)d_in[6];
    const float* Wo = (const float*)d_in[7];
    const float* bo = (const float*)d_in[8];
    float* y = (float*)d_out;

    bf16* qkv = (bf16*)d_ws;                        // 3 * B*N*CK bf16
    bf16* ao  = qkv + (size_t)3 * BB * NN * CK;     // B*N*CK bf16

    k_qkv<<<dim3(NN / 128, 3, BB), 256, 0, stream>>>(x, Wq, bq, Wk, bk, Wv, bv, qkv);
    k_attn<<<dim3(NN / 64, BB), 256, 0, stream>>>(qkv, ao);
    k_out<<<dim3(NN / 128, C / 64, BB), 256, 0, stream>>>(x, Wo, bo, ao, y);
}